// Round 1
// baseline (896.249 us; speedup 1.0000x reference)
//
#include <hip/hip_runtime.h>
#include <math.h>

#define Bn 16
#define Sn 1024
#define Hn 1024
static const size_t SH = (size_t)Sn * Hn;          // 1,048,576
static const size_t BSH = (size_t)Bn * Sn * Hn;    // 16,777,216

// ---------------------------------------------------------------------------
// K1: c1[b,h] = ht[b,:] . W_attn[h, 0:H] + b_attn[h]
// one wave per (b,h); block = 4 waves
// ---------------------------------------------------------------------------
__global__ __launch_bounds__(256) void c1_kernel(const float* __restrict__ ht,
                                                 const float* __restrict__ W_attn,
                                                 const float* __restrict__ b_attn,
                                                 float* __restrict__ c1) {
  int wid = blockIdx.x * 4 + (threadIdx.x >> 6);
  int lane = threadIdx.x & 63;
  int b = wid >> 10;
  int h = wid & 1023;
  const float* w = W_attn + (size_t)h * 2048;
  const float* x = ht + b * 1024;
  float s = 0.f;
#pragma unroll 4
  for (int k = lane; k < 1024; k += 64) s = fmaf(w[k], x[k], s);
#pragma unroll
  for (int off = 32; off; off >>= 1) s += __shfl_down(s, off, 64);
  if (lane == 0) c1[wid] = s + b_attn[h];
}

// ---------------------------------------------------------------------------
// K2: E[b,s,h] = tanh( sum_k enc[b,s,k] * W_attn[h, H+k] + c1[b,h] )
// 128x128 tile, BK=8, 8x8 microtile, fp32
// ---------------------------------------------------------------------------
__global__ __launch_bounds__(256) void energy_kernel(const float* __restrict__ enc,
                                                     const float* __restrict__ W_attn,
                                                     const float* __restrict__ c1,
                                                     float* __restrict__ E) {
  __shared__ float Ast[8][128];  // k-major: Ast[kk][row]
  __shared__ float Bst[8][128];  // k-major: Bst[kk][col]
  const int b = blockIdx.z;
  const int row0 = blockIdx.y * 128;
  const int col0 = blockIdx.x * 128;
  const int t = threadIdx.x;
  const int tx = t & 15, ty = t >> 4;
  const float* A = enc + (size_t)b * SH;

  float acc[8][8];
#pragma unroll
  for (int i = 0; i < 8; ++i)
#pragma unroll
    for (int j = 0; j < 8; ++j) acc[i][j] = 0.f;

  const int lr = t >> 1;        // 0..127
  const int lh = (t & 1) * 4;   // 0 or 4

  for (int k0 = 0; k0 < 1024; k0 += 8) {
    const float4 va = *(const float4*)(A + (size_t)(row0 + lr) * 1024 + k0 + lh);
    const float4 vb = *(const float4*)(W_attn + (size_t)(col0 + lr) * 2048 + 1024 + k0 + lh);
    __syncthreads();
    Ast[lh + 0][lr] = va.x; Ast[lh + 1][lr] = va.y;
    Ast[lh + 2][lr] = va.z; Ast[lh + 3][lr] = va.w;
    Bst[lh + 0][lr] = vb.x; Bst[lh + 1][lr] = vb.y;
    Bst[lh + 2][lr] = vb.z; Bst[lh + 3][lr] = vb.w;
    __syncthreads();
#pragma unroll
    for (int kk = 0; kk < 8; ++kk) {
      const float4 a0 = *(const float4*)&Ast[kk][ty * 8];
      const float4 a1 = *(const float4*)&Ast[kk][ty * 8 + 4];
      const float4 b0 = *(const float4*)&Bst[kk][tx * 4];
      const float4 b1 = *(const float4*)&Bst[kk][64 + tx * 4];
      const float av[8] = {a0.x, a0.y, a0.z, a0.w, a1.x, a1.y, a1.z, a1.w};
      const float bv[8] = {b0.x, b0.y, b0.z, b0.w, b1.x, b1.y, b1.z, b1.w};
#pragma unroll
      for (int i = 0; i < 8; ++i)
#pragma unroll
        for (int j = 0; j < 8; ++j) acc[i][j] = fmaf(av[i], bv[j], acc[i][j]);
    }
  }

  // epilogue: + c1, tanh, store
  float c1v[8];
#pragma unroll
  for (int j = 0; j < 4; ++j) {
    c1v[j]     = c1[b * 1024 + col0 + tx * 4 + j];
    c1v[4 + j] = c1[b * 1024 + col0 + 64 + tx * 4 + j];
  }
  float* Eb = E + (size_t)b * SH;
#pragma unroll
  for (int i = 0; i < 8; ++i) {
    const int row = row0 + ty * 8 + i;
    float4 o0, o1;
    o0.x = tanhf(acc[i][0] + c1v[0]);
    o0.y = tanhf(acc[i][1] + c1v[1]);
    o0.z = tanhf(acc[i][2] + c1v[2]);
    o0.w = tanhf(acc[i][3] + c1v[3]);
    o1.x = tanhf(acc[i][4] + c1v[4]);
    o1.y = tanhf(acc[i][5] + c1v[5]);
    o1.z = tanhf(acc[i][6] + c1v[6]);
    o1.w = tanhf(acc[i][7] + c1v[7]);
    *(float4*)(Eb + (size_t)row * 1024 + col0 + tx * 4) = o0;
    *(float4*)(Eb + (size_t)row * 1024 + col0 + 64 + tx * 4) = o1;
  }
}

// ---------------------------------------------------------------------------
// K3: in-place column softmax over s: E[b,:,h] -> exp/colsum
// block = 64 columns x 4 s-groups (256 threads); grid = B * H/64
// ---------------------------------------------------------------------------
__global__ __launch_bounds__(256) void softmax_kernel(float* __restrict__ E) {
  const int b = blockIdx.x >> 4;
  const int hg = blockIdx.x & 15;
  const int l = threadIdx.x & 63;
  const int sg = threadIdx.x >> 6;
  float* col = E + (size_t)b * SH + hg * 64 + l;
  const int s0 = sg * 256;
  float sum = 0.f;
#pragma unroll 8
  for (int s = s0; s < s0 + 256; ++s) sum += __expf(col[(size_t)s * 1024]);
  __shared__ float red[4][64];
  red[sg][l] = sum;
  __syncthreads();
  const float inv = 1.f / (red[0][l] + red[1][l] + red[2][l] + red[3][l]);
#pragma unroll 8
  for (int s = s0; s < s0 + 256; ++s) {
    const size_t idx = (size_t)s * 1024;
    col[idx] = __expf(col[idx]) * inv;
  }
}

// ---------------------------------------------------------------------------
// K4: context[b,s,h] = sum_k aw[b,s,k] * enc[b,k,h]
// same tiling; B operand is k-major (non-transposed)
// ---------------------------------------------------------------------------
__global__ __launch_bounds__(256) void context_kernel(const float* __restrict__ aw,
                                                      const float* __restrict__ enc,
                                                      float* __restrict__ ctx) {
  __shared__ float Ast[8][128];
  __shared__ float Bst[8][128];
  const int b = blockIdx.z;
  const int row0 = blockIdx.y * 128;
  const int col0 = blockIdx.x * 128;
  const int t = threadIdx.x;
  const int tx = t & 15, ty = t >> 4;
  const float* A = aw + (size_t)b * SH;
  const float* Bm = enc + (size_t)b * SH;

  float acc[8][8];
#pragma unroll
  for (int i = 0; i < 8; ++i)
#pragma unroll
    for (int j = 0; j < 8; ++j) acc[i][j] = 0.f;

  const int lr = t >> 1;
  const int lh = (t & 1) * 4;
  const int bk = t >> 5;          // 0..7
  const int bc = (t & 31) * 4;    // 0..124

  for (int k0 = 0; k0 < 1024; k0 += 8) {
    const float4 va = *(const float4*)(A + (size_t)(row0 + lr) * 1024 + k0 + lh);
    const float4 vb = *(const float4*)(Bm + (size_t)(k0 + bk) * 1024 + col0 + bc);
    __syncthreads();
    Ast[lh + 0][lr] = va.x; Ast[lh + 1][lr] = va.y;
    Ast[lh + 2][lr] = va.z; Ast[lh + 3][lr] = va.w;
    *(float4*)&Bst[bk][bc] = vb;
    __syncthreads();
#pragma unroll
    for (int kk = 0; kk < 8; ++kk) {
      const float4 a0 = *(const float4*)&Ast[kk][ty * 8];
      const float4 a1 = *(const float4*)&Ast[kk][ty * 8 + 4];
      const float4 b0 = *(const float4*)&Bst[kk][tx * 4];
      const float4 b1 = *(const float4*)&Bst[kk][64 + tx * 4];
      const float av[8] = {a0.x, a0.y, a0.z, a0.w, a1.x, a1.y, a1.z, a1.w};
      const float bv[8] = {b0.x, b0.y, b0.z, b0.w, b1.x, b1.y, b1.z, b1.w};
#pragma unroll
      for (int i = 0; i < 8; ++i)
#pragma unroll
        for (int j = 0; j < 8; ++j) acc[i][j] = fmaf(av[i], bv[j], acc[i][j]);
    }
  }

  float* Cb = ctx + (size_t)b * SH;
#pragma unroll
  for (int i = 0; i < 8; ++i) {
    const int row = row0 + ty * 8 + i;
    float4 o0, o1;
    o0.x = acc[i][0]; o0.y = acc[i][1]; o0.z = acc[i][2]; o0.w = acc[i][3];
    o1.x = acc[i][4]; o1.y = acc[i][5]; o1.z = acc[i][6]; o1.w = acc[i][7];
    *(float4*)(Cb + (size_t)row * 1024 + col0 + tx * 4) = o0;
    *(float4*)(Cb + (size_t)row * 1024 + col0 + 64 + tx * 4) = o1;
  }
}

// ---------------------------------------------------------------------------
extern "C" void kernel_launch(void* const* d_in, const int* in_sizes, int n_in,
                              void* d_out, int out_size, void* d_ws, size_t ws_size,
                              hipStream_t stream) {
  (void)in_sizes; (void)n_in; (void)out_size; (void)ws_size;
  const float* ht     = (const float*)d_in[0];
  const float* enc    = (const float*)d_in[1];
  const float* W_attn = (const float*)d_in[2];
  const float* b_attn = (const float*)d_in[3];
  // d_in[4] (W_v) is dead code in the reference

  float* ctx = (float*)d_out;          // [B,S,H] context
  float* aw  = ctx + BSH;              // [B,S,H] attention_weights (also used as E scratch)
  float* c1  = (float*)d_ws;           // [B,H]

  c1_kernel<<<Bn * Hn / 4, 256, 0, stream>>>(ht, W_attn, b_attn, c1);

  dim3 g(8, 8, Bn);
  energy_kernel<<<g, 256, 0, stream>>>(enc, W_attn, c1, aw);
  softmax_kernel<<<Bn * (Hn / 64), 256, 0, stream>>>(aw);
  context_kernel<<<g, 256, 0, stream>>>(aw, enc, ctx);
}

// Round 2
// 254.201 us; speedup vs baseline: 3.5258x; 3.5258x over previous
//
#include <hip/hip_runtime.h>
#include <math.h>

#define Bn 16
#define Sn 1024
#define Hn 1024
static const size_t SH = (size_t)Sn * Hn;          // 1,048,576
static const size_t BSH = (size_t)Bn * Sn * Hn;    // 16,777,216

typedef __attribute__((ext_vector_type(8))) short short8;
typedef __attribute__((ext_vector_type(4))) float f32x4;

// round-to-nearest-even fp32 -> bf16
__device__ __forceinline__ short bfr(float f) {
  union { float f; unsigned u; } v; v.f = f;
  unsigned r = (v.u + 0x7FFFu + ((v.u >> 16) & 1u)) >> 16;
  return (short)r;
}
__device__ __forceinline__ short8 cvt8(float4 x, float4 y) {
  short8 r;
  r[0] = bfr(x.x); r[1] = bfr(x.y); r[2] = bfr(x.z); r[3] = bfr(x.w);
  r[4] = bfr(y.x); r[5] = bfr(y.y); r[6] = bfr(y.z); r[7] = bfr(y.w);
  return r;
}

// chunk swizzle: 4 chunks of 8 bf16 per 32-elem row; spreads b128 accesses
// across LDS 16B-granules -> 2-way aliasing (free) instead of 8-way
#define SWZ(r, c) ((c) ^ (((r) >> 1) & 3))

// ---------------------------------------------------------------------------
// K1: c1[b,h] = ht[b,:] . W_attn[h, 0:H] + b_attn[h]
// ---------------------------------------------------------------------------
__global__ __launch_bounds__(256) void c1_kernel(const float* __restrict__ ht,
                                                 const float* __restrict__ W_attn,
                                                 const float* __restrict__ b_attn,
                                                 float* __restrict__ c1) {
  int wid = blockIdx.x * 4 + (threadIdx.x >> 6);
  int lane = threadIdx.x & 63;
  int b = wid >> 10;
  int h = wid & 1023;
  const float* w = W_attn + (size_t)h * 2048;
  const float* x = ht + b * 1024;
  float s = 0.f;
#pragma unroll 4
  for (int k = lane; k < 1024; k += 64) s = fmaf(w[k], x[k], s);
#pragma unroll
  for (int off = 32; off; off >>= 1) s += __shfl_down(s, off, 64);
  if (lane == 0) c1[wid] = s + b_attn[h];
}

// ---------------------------------------------------------------------------
// K2: E[b,s,h] = tanh( enc[b,s,:] . W2[h,:] + c1[b,h] )   (W2 = W_attn[:,H:])
// 128x128 tile, BK=32, bf16 MFMA 16x16x32, fp32->bf16 convert during staging
// ---------------------------------------------------------------------------
__global__ __launch_bounds__(256) void energy_mfma(const float* __restrict__ enc,
                                                   const float* __restrict__ W_attn,
                                                   const float* __restrict__ c1,
                                                   float* __restrict__ E) {
  __shared__ __align__(16) short Ast[128 * 32];
  __shared__ __align__(16) short Bst[128 * 32];
  const int b = blockIdx.z;
  const int row0 = blockIdx.y * 128;
  const int col0 = blockIdx.x * 128;
  const int t = threadIdx.x;
  const int l = t & 63;
  const int w = t >> 6;
  const int wr = w >> 1, wc = w & 1;
  const int fr = l & 15, kg = l >> 4;

  // staging assignment: thread t -> row t>>1, chunks (t&1)*2 + {0,1}
  const int sr = t >> 1;
  const int sc0 = (t & 1) * 2;
  const float* arow = enc + (size_t)b * SH + (size_t)(row0 + sr) * 1024;
  const float* brow = W_attn + (size_t)(col0 + sr) * 2048 + 1024;

  f32x4 acc[4][4] = {};

  for (int k0 = 0; k0 < 1024; k0 += 32) {
    const float4 a0 = *(const float4*)(arow + k0 + sc0 * 8);
    const float4 a1 = *(const float4*)(arow + k0 + sc0 * 8 + 4);
    const float4 a2 = *(const float4*)(arow + k0 + sc0 * 8 + 8);
    const float4 a3 = *(const float4*)(arow + k0 + sc0 * 8 + 12);
    const float4 b0 = *(const float4*)(brow + k0 + sc0 * 8);
    const float4 b1 = *(const float4*)(brow + k0 + sc0 * 8 + 4);
    const float4 b2 = *(const float4*)(brow + k0 + sc0 * 8 + 8);
    const float4 b3 = *(const float4*)(brow + k0 + sc0 * 8 + 12);
    __syncthreads();  // prior iteration's reads done
    *(short8*)&Ast[sr * 32 + SWZ(sr, sc0) * 8]     = cvt8(a0, a1);
    *(short8*)&Ast[sr * 32 + SWZ(sr, sc0 + 1) * 8] = cvt8(a2, a3);
    *(short8*)&Bst[sr * 32 + SWZ(sr, sc0) * 8]     = cvt8(b0, b1);
    *(short8*)&Bst[sr * 32 + SWZ(sr, sc0 + 1) * 8] = cvt8(b2, b3);
    __syncthreads();
    short8 af[4], bf[4];
#pragma unroll
    for (int m = 0; m < 4; ++m) {
      const int r = wr * 64 + m * 16 + fr;
      af[m] = *(const short8*)&Ast[r * 32 + SWZ(r, kg) * 8];
    }
#pragma unroll
    for (int n = 0; n < 4; ++n) {
      const int r = wc * 64 + n * 16 + fr;
      bf[n] = *(const short8*)&Bst[r * 32 + SWZ(r, kg) * 8];
    }
#pragma unroll
    for (int m = 0; m < 4; ++m)
#pragma unroll
      for (int n = 0; n < 4; ++n)
        acc[m][n] = __builtin_amdgcn_mfma_f32_16x16x32_bf16(af[m], bf[n], acc[m][n], 0, 0, 0);
  }

  // epilogue: + c1, tanh, store   D: col = lane&15, row = (lane>>4)*4 + reg
  float* Eb = E + (size_t)b * SH;
#pragma unroll
  for (int n = 0; n < 4; ++n) {
    const int col = col0 + wc * 64 + n * 16 + fr;
    const float c1v = c1[b * 1024 + col];
#pragma unroll
    for (int m = 0; m < 4; ++m) {
      const int r0 = row0 + wr * 64 + m * 16 + kg * 4;
#pragma unroll
      for (int r = 0; r < 4; ++r) {
        const float x = acc[m][n][r] + c1v;
        const float e = __expf(2.f * x);               // tanh = (e^2x-1)/(e^2x+1)
        Eb[(size_t)(r0 + r) * 1024 + col] = (e - 1.f) / (e + 1.f);
      }
    }
  }
}

// ---------------------------------------------------------------------------
// K3: in-place column softmax over s
// ---------------------------------------------------------------------------
__global__ __launch_bounds__(256) void softmax_kernel(float* __restrict__ E) {
  const int b = blockIdx.x >> 4;
  const int hg = blockIdx.x & 15;
  const int l = threadIdx.x & 63;
  const int sg = threadIdx.x >> 6;
  float* col = E + (size_t)b * SH + hg * 64 + l;
  const int s0 = sg * 256;
  float sum = 0.f;
#pragma unroll 8
  for (int s = s0; s < s0 + 256; ++s) sum += __expf(col[(size_t)s * 1024]);
  __shared__ float red[4][64];
  red[sg][l] = sum;
  __syncthreads();
  const float inv = 1.f / (red[0][l] + red[1][l] + red[2][l] + red[3][l]);
#pragma unroll 8
  for (int s = s0; s < s0 + 256; ++s) {
    const size_t idx = (size_t)s * 1024;
    col[idx] = __expf(col[idx]) * inv;
  }
}

// ---------------------------------------------------------------------------
// K4: context[b,s,h] = sum_k aw[b,s,k] * enc[b,k,h]   (B operand k-major ->
// transpose during staging via per-column strided loads)
// ---------------------------------------------------------------------------
__global__ __launch_bounds__(256) void context_mfma(const float* __restrict__ aw,
                                                    const float* __restrict__ enc,
                                                    float* __restrict__ ctx) {
  __shared__ __align__(16) short Ast[128 * 32];
  __shared__ __align__(16) short Bst[128 * 32];
  const int b = blockIdx.z;
  const int row0 = blockIdx.y * 128;
  const int col0 = blockIdx.x * 128;
  const int t = threadIdx.x;
  const int l = t & 63;
  const int w = t >> 6;
  const int wr = w >> 1, wc = w & 1;
  const int fr = l & 15, kg = l >> 4;

  const int sr = t >> 1;
  const int sc0 = (t & 1) * 2;
  const float* arow = aw + (size_t)b * SH + (size_t)(row0 + sr) * 1024;

  // B staging: thread t owns col (t&127), k-chunks (t>>7)*2 + {0,1}
  const int bcol = t & 127;
  const int kb0 = (t >> 7) * 2;
  const float* bcolp = enc + (size_t)b * SH + col0 + bcol;

  f32x4 acc[4][4] = {};

  for (int k0 = 0; k0 < 1024; k0 += 32) {
    const float4 a0 = *(const float4*)(arow + k0 + sc0 * 8);
    const float4 a1 = *(const float4*)(arow + k0 + sc0 * 8 + 4);
    const float4 a2 = *(const float4*)(arow + k0 + sc0 * 8 + 8);
    const float4 a3 = *(const float4*)(arow + k0 + sc0 * 8 + 12);
    float bv[2][8];
#pragma unroll
    for (int j = 0; j < 2; ++j)
#pragma unroll
      for (int i = 0; i < 8; ++i)
        bv[j][i] = bcolp[(size_t)(k0 + (kb0 + j) * 8 + i) * 1024];
    __syncthreads();
    *(short8*)&Ast[sr * 32 + SWZ(sr, sc0) * 8]     = cvt8(a0, a1);
    *(short8*)&Ast[sr * 32 + SWZ(sr, sc0 + 1) * 8] = cvt8(a2, a3);
#pragma unroll
    for (int j = 0; j < 2; ++j) {
      short8 pk;
#pragma unroll
      for (int i = 0; i < 8; ++i) pk[i] = bfr(bv[j][i]);
      *(short8*)&Bst[bcol * 32 + SWZ(bcol, kb0 + j) * 8] = pk;
    }
    __syncthreads();
    short8 af[4], bf[4];
#pragma unroll
    for (int m = 0; m < 4; ++m) {
      const int r = wr * 64 + m * 16 + fr;
      af[m] = *(const short8*)&Ast[r * 32 + SWZ(r, kg) * 8];
    }
#pragma unroll
    for (int n = 0; n < 4; ++n) {
      const int r = wc * 64 + n * 16 + fr;
      bf[n] = *(const short8*)&Bst[r * 32 + SWZ(r, kg) * 8];
    }
#pragma unroll
    for (int m = 0; m < 4; ++m)
#pragma unroll
      for (int n = 0; n < 4; ++n)
        acc[m][n] = __builtin_amdgcn_mfma_f32_16x16x32_bf16(af[m], bf[n], acc[m][n], 0, 0, 0);
  }

  float* Cb = ctx + (size_t)b * SH;
#pragma unroll
  for (int n = 0; n < 4; ++n) {
    const int col = col0 + wc * 64 + n * 16 + fr;
#pragma unroll
    for (int m = 0; m < 4; ++m) {
      const int r0 = row0 + wr * 64 + m * 16 + kg * 4;
#pragma unroll
      for (int r = 0; r < 4; ++r)
        Cb[(size_t)(r0 + r) * 1024 + col] = acc[m][n][r];
    }
  }
}

// ---------------------------------------------------------------------------
extern "C" void kernel_launch(void* const* d_in, const int* in_sizes, int n_in,
                              void* d_out, int out_size, void* d_ws, size_t ws_size,
                              hipStream_t stream) {
  (void)in_sizes; (void)n_in; (void)out_size; (void)ws_size;
  const float* ht     = (const float*)d_in[0];
  const float* enc    = (const float*)d_in[1];
  const float* W_attn = (const float*)d_in[2];
  const float* b_attn = (const float*)d_in[3];
  // d_in[4] (W_v) is dead code in the reference

  float* ctx = (float*)d_out;          // [B,S,H] context
  float* aw  = ctx + BSH;              // [B,S,H] attention_weights (E scratch)
  float* c1  = (float*)d_ws;           // [B,H]

  c1_kernel<<<Bn * Hn / 4, 256, 0, stream>>>(ht, W_attn, b_attn, c1);

  dim3 g(8, 8, Bn);
  energy_mfma<<<g, 256, 0, stream>>>(enc, W_attn, c1, aw);
  softmax_kernel<<<Bn * (Hn / 64), 256, 0, stream>>>(aw);
  context_mfma<<<g, 256, 0, stream>>>(aw, enc, ctx);
}

// Round 3
// 245.088 us; speedup vs baseline: 3.6568x; 1.0372x over previous
//
#include <hip/hip_runtime.h>
#include <math.h>

#define Bn 16
#define Sn 1024
#define Hn 1024
static const size_t SH = (size_t)Sn * Hn;          // 1,048,576
static const size_t BSH = (size_t)Bn * Sn * Hn;    // 16,777,216

typedef __attribute__((ext_vector_type(8))) short short8;
typedef __attribute__((ext_vector_type(4))) float f32x4;

// async global->LDS, 16B per lane; LDS dest is wave-uniform base + lane*16
#define GLD16(gp, lp) __builtin_amdgcn_global_load_lds( \
    (const __attribute__((address_space(1))) void*)(gp), \
    (__attribute__((address_space(3))) void*)(lp), 16, 0, 0)

// round-to-nearest-even fp32 -> bf16
__device__ __forceinline__ short bfr(float f) {
  union { float f; unsigned u; } v; v.f = f;
  unsigned r = (v.u + 0x7FFFu + ((v.u >> 16) & 1u)) >> 16;
  return (short)r;
}
__device__ __forceinline__ short8 cvt8(float4 x, float4 y) {
  short8 r;
  r[0] = bfr(x.x); r[1] = bfr(x.y); r[2] = bfr(x.z); r[3] = bfr(x.w);
  r[4] = bfr(y.x); r[5] = bfr(y.y); r[6] = bfr(y.z); r[7] = bfr(y.w);
  return r;
}

// granule swizzle within each 32-element k-block (4 granules of 8 bf16):
// storage granule = logical ^ ((row>>1)&3)  -> 2-way LDS bank aliasing (free)
__device__ __forceinline__ int swzg(int row, int g) {
  return (g & ~3) | ((g & 3) ^ ((row >> 1) & 3));
}

// ---------------------------------------------------------------------------
// cvt_enc: enc fp32 [row][1024] -> enc_bf bf16, pre-swizzled (row = b*1024+s)
// ---------------------------------------------------------------------------
__global__ __launch_bounds__(256) void cvt_enc_kernel(const float* __restrict__ enc,
                                                      short* __restrict__ enc_bf) {
  const int g = blockIdx.x * 256 + threadIdx.x;   // granule id
  const int row = g >> 7;
  const int cs = g & 127;
  const float4 x = *(const float4*)(enc + (size_t)row * 1024 + cs * 8);
  const float4 y = *(const float4*)(enc + (size_t)row * 1024 + cs * 8 + 4);
  *(short8*)(enc_bf + (size_t)row * 1024 + swzg(row, cs) * 8) = cvt8(x, y);
}

// ---------------------------------------------------------------------------
// cvt_w2: W_attn[h][1024..2047] -> W2_bf[h][k] bf16, pre-swizzled
// ---------------------------------------------------------------------------
__global__ __launch_bounds__(256) void cvt_w2_kernel(const float* __restrict__ W_attn,
                                                     short* __restrict__ W2_bf) {
  const int g = blockIdx.x * 256 + threadIdx.x;
  const int h = g >> 7;
  const int cs = g & 127;
  const float4 x = *(const float4*)(W_attn + (size_t)h * 2048 + 1024 + cs * 8);
  const float4 y = *(const float4*)(W_attn + (size_t)h * 2048 + 1024 + cs * 8 + 4);
  *(short8*)(W2_bf + (size_t)h * 1024 + swzg(h, cs) * 8) = cvt8(x, y);
}

// ---------------------------------------------------------------------------
// cvt_encT: enc[b][s][h] -> encT[b][h][s] bf16, pre-swizzled (k = s)
// ---------------------------------------------------------------------------
__global__ __launch_bounds__(256) void cvt_encT_kernel(const float* __restrict__ enc,
                                                       short* __restrict__ encT) {
  __shared__ float tile[64][65];
  const int b = blockIdx.z;
  const int s0 = blockIdx.y * 64, h0 = blockIdx.x * 64;
  const int t = threadIdx.x;
  const int tr = t >> 4, tc = t & 15;
  const float* src = enc + (size_t)b * SH;
#pragma unroll
  for (int i = 0; i < 4; ++i) {
    const int s = i * 16 + tr;
    const float4 v = *(const float4*)(src + (size_t)(s0 + s) * 1024 + h0 + tc * 4);
    tile[s][tc * 4 + 0] = v.x; tile[s][tc * 4 + 1] = v.y;
    tile[s][tc * 4 + 2] = v.z; tile[s][tc * 4 + 3] = v.w;
  }
  __syncthreads();
  const int hr = t >> 2, cs = t & 3;
  const int h = h0 + hr;
#pragma unroll
  for (int blk = 0; blk < 2; ++blk) {
    const int sg = blk * 4 + cs;                 // local granule 0..7
    const int gl = (s0 >> 3) + sg;               // global logical granule
    const int gst = (gl & ~3) | ((gl & 3) ^ ((h >> 1) & 3));
    short8 pk;
#pragma unroll
    for (int j = 0; j < 8; ++j) pk[j] = bfr(tile[sg * 8 + j][hr]);
    *(short8*)(encT + (size_t)b * SH + (size_t)h * 1024 + gst * 8) = pk;
  }
}

// ---------------------------------------------------------------------------
// c1: c1[b,h] = ht[b,:] . W_attn[h, 0:H] + b_attn[h]
// ---------------------------------------------------------------------------
__global__ __launch_bounds__(256) void c1_kernel(const float* __restrict__ ht,
                                                 const float* __restrict__ W_attn,
                                                 const float* __restrict__ b_attn,
                                                 float* __restrict__ c1) {
  int wid = blockIdx.x * 4 + (threadIdx.x >> 6);
  int lane = threadIdx.x & 63;
  int b = wid >> 10;
  int h = wid & 1023;
  const float* w = W_attn + (size_t)h * 2048;
  const float* x = ht + b * 1024;
  float s = 0.f;
#pragma unroll 4
  for (int k = lane; k < 1024; k += 64) s = fmaf(w[k], x[k], s);
#pragma unroll
  for (int off = 32; off; off >>= 1) s += __shfl_down(s, off, 64);
  if (lane == 0) c1[wid] = s + b_attn[h];
}

// ---------------------------------------------------------------------------
// GEMM1: X[b,s,h] = exp(tanh(enc_bf[s,:] . W2_bf[h,:] + c1[b,h]))
// m97 structure: 128x128 tile, BK=32, global_load_lds staging (pre-swizzled)
// ---------------------------------------------------------------------------
__global__ __launch_bounds__(256) void energy_mfma2(const short* __restrict__ enc_bf,
                                                    const short* __restrict__ W2_bf,
                                                    const float* __restrict__ c1,
                                                    float* __restrict__ X) {
  __shared__ __align__(16) short Ast[128 * 32];
  __shared__ __align__(16) short Bst[128 * 32];
  const int b = blockIdx.z;
  const int row0 = blockIdx.y * 128;
  const int col0 = blockIdx.x * 128;
  const int t = threadIdx.x;
  const int l = t & 63;
  const int w = t >> 6;
  const int wr = w >> 1, wc = w & 1;
  const int fr = l & 15, kg = l >> 4;

  const short* Abase = enc_bf + (size_t)b * SH + (size_t)(row0 + w * 32 + (l >> 2)) * 1024 + (l & 3) * 8;
  const short* Bbase = W2_bf + (size_t)(col0 + w * 32 + (l >> 2)) * 1024 + (l & 3) * 8;
  short* Alds = Ast + w * 1024;   // wave chunk: 1024 shorts = 2KB (32 rows)
  short* Blds = Bst + w * 1024;

  f32x4 acc[4][4] = {};

  for (int k0 = 0; k0 < 1024; k0 += 32) {
    GLD16(Abase + k0, Alds);
    GLD16(Abase + k0 + 16 * 1024, Alds + 512);
    GLD16(Bbase + k0, Blds);
    GLD16(Bbase + k0 + 16 * 1024, Blds + 512);
    __syncthreads();   // drains vmcnt: LDS tile ready
    short8 af[4], bf4[4];
#pragma unroll
    for (int m = 0; m < 4; ++m) {
      const int r = wr * 64 + m * 16 + fr;
      af[m] = *(const short8*)&Ast[r * 32 + ((kg ^ ((r >> 1) & 3)) << 3)];
    }
#pragma unroll
    for (int n = 0; n < 4; ++n) {
      const int r = wc * 64 + n * 16 + fr;
      bf4[n] = *(const short8*)&Bst[r * 32 + ((kg ^ ((r >> 1) & 3)) << 3)];
    }
#pragma unroll
    for (int m = 0; m < 4; ++m)
#pragma unroll
      for (int n = 0; n < 4; ++n)
        acc[m][n] = __builtin_amdgcn_mfma_f32_16x16x32_bf16(af[m], bf4[n], acc[m][n], 0, 0, 0);
    __syncthreads();   // reads done before next stage overwrites
  }

  // epilogue: X = exp(tanh(acc + c1))
  float* Xb = X + (size_t)b * SH;
#pragma unroll
  for (int n = 0; n < 4; ++n) {
    const int col = col0 + wc * 64 + n * 16 + fr;
    const float c1v = c1[b * 1024 + col];
#pragma unroll
    for (int m = 0; m < 4; ++m) {
      const int r0 = row0 + wr * 64 + m * 16 + kg * 4;
#pragma unroll
      for (int r = 0; r < 4; ++r) {
        const float x = acc[m][n][r] + c1v;
        const float e = __expf(2.f * x);
        Xb[(size_t)(r0 + r) * 1024 + col] = __expf((e - 1.f) / (e + 1.f));
      }
    }
  }
}

// ---------------------------------------------------------------------------
// norm: column-normalize X over s (X already holds exp values)
// ---------------------------------------------------------------------------
__global__ __launch_bounds__(256) void norm_kernel(float* __restrict__ X) {
  const int b = blockIdx.x >> 4;
  const int hg = blockIdx.x & 15;
  const int l = threadIdx.x & 63;
  const int sg = threadIdx.x >> 6;
  float* col = X + (size_t)b * SH + hg * 64 + l;
  const int s0 = sg * 256;
  float sum = 0.f;
#pragma unroll 8
  for (int s = s0; s < s0 + 256; ++s) sum += col[(size_t)s * 1024];
  __shared__ float red[4][64];
  red[sg][l] = sum;
  __syncthreads();
  const float inv = 1.f / (red[0][l] + red[1][l] + red[2][l] + red[3][l]);
#pragma unroll 8
  for (int s = s0; s < s0 + 256; ++s) col[(size_t)s * 1024] *= inv;
}

// ---------------------------------------------------------------------------
// GEMM2 fast: ctx[b,s,h] = sum_k aw[s,k] * encT[h,k]
// A reg-staged (fp32->bf16) with 1-iter prefetch; B via global_load_lds
// ---------------------------------------------------------------------------
__global__ __launch_bounds__(256) void context_fast(const float* __restrict__ aw,
                                                    const short* __restrict__ encT,
                                                    float* __restrict__ ctx) {
  __shared__ __align__(16) short Ast[128 * 32];
  __shared__ __align__(16) short Bst[128 * 32];
  const int b = blockIdx.z;
  const int row0 = blockIdx.y * 128;
  const int col0 = blockIdx.x * 128;
  const int t = threadIdx.x;
  const int l = t & 63;
  const int w = t >> 6;
  const int wr = w >> 1, wc = w & 1;
  const int fr = l & 15, kg = l >> 4;

  const int sr = t >> 1;
  const int sc0 = (t & 1) * 2;
  const float* arow = aw + (size_t)b * SH + (size_t)(row0 + sr) * 1024;
  const short* Bbase = encT + (size_t)b * SH + (size_t)(col0 + w * 32 + (l >> 2)) * 1024 + (l & 3) * 8;
  short* Blds = Bst + w * 1024;

  float4 a0 = *(const float4*)(arow + sc0 * 8);
  float4 a1 = *(const float4*)(arow + sc0 * 8 + 4);
  float4 a2 = *(const float4*)(arow + sc0 * 8 + 8);
  float4 a3 = *(const float4*)(arow + sc0 * 8 + 12);

  f32x4 acc[4][4] = {};

  for (int k0 = 0; k0 < 1024; k0 += 32) {
    GLD16(Bbase + k0, Blds);
    GLD16(Bbase + k0 + 16 * 1024, Blds + 512);
    *(short8*)&Ast[sr * 32 + ((sc0 ^ ((sr >> 1) & 3)) << 3)]       = cvt8(a0, a1);
    *(short8*)&Ast[sr * 32 + (((sc0 + 1) ^ ((sr >> 1) & 3)) << 3)] = cvt8(a2, a3);
    if (k0 != 992) {
      a0 = *(const float4*)(arow + k0 + 32 + sc0 * 8);
      a1 = *(const float4*)(arow + k0 + 32 + sc0 * 8 + 4);
      a2 = *(const float4*)(arow + k0 + 32 + sc0 * 8 + 8);
      a3 = *(const float4*)(arow + k0 + 32 + sc0 * 8 + 12);
    }
    __syncthreads();
    short8 af[4], bf4[4];
#pragma unroll
    for (int m = 0; m < 4; ++m) {
      const int r = wr * 64 + m * 16 + fr;
      af[m] = *(const short8*)&Ast[r * 32 + ((kg ^ ((r >> 1) & 3)) << 3)];
    }
#pragma unroll
    for (int n = 0; n < 4; ++n) {
      const int r = wc * 64 + n * 16 + fr;
      bf4[n] = *(const short8*)&Bst[r * 32 + ((kg ^ ((r >> 1) & 3)) << 3)];
    }
#pragma unroll
    for (int m = 0; m < 4; ++m)
#pragma unroll
      for (int n = 0; n < 4; ++n)
        acc[m][n] = __builtin_amdgcn_mfma_f32_16x16x32_bf16(af[m], bf4[n], acc[m][n], 0, 0, 0);
    __syncthreads();
  }

  float* Cb = ctx + (size_t)b * SH;
#pragma unroll
  for (int n = 0; n < 4; ++n) {
    const int col = col0 + wc * 64 + n * 16 + fr;
#pragma unroll
    for (int m = 0; m < 4; ++m) {
      const int r0 = row0 + wr * 64 + m * 16 + kg * 4;
#pragma unroll
      for (int r = 0; r < 4; ++r)
        Cb[(size_t)(r0 + r) * 1024 + col] = acc[m][n][r];
    }
  }
}

// ---------------------------------------------------------------------------
// GEMM2 fallback (small ws): R1's reg-staged version, B transposed in staging
// ---------------------------------------------------------------------------
__global__ __launch_bounds__(256) void context_mfma(const float* __restrict__ aw,
                                                    const float* __restrict__ enc,
                                                    float* __restrict__ ctx) {
  __shared__ __align__(16) short Ast[128 * 32];
  __shared__ __align__(16) short Bst[128 * 32];
  const int b = blockIdx.z;
  const int row0 = blockIdx.y * 128;
  const int col0 = blockIdx.x * 128;
  const int t = threadIdx.x;
  const int l = t & 63;
  const int w = t >> 6;
  const int wr = w >> 1, wc = w & 1;
  const int fr = l & 15, kg = l >> 4;

  const int sr = t >> 1;
  const int sc0 = (t & 1) * 2;
  const float* arow = aw + (size_t)b * SH + (size_t)(row0 + sr) * 1024;
  const int bcol = t & 127;
  const int kb0 = (t >> 7) * 2;
  const float* bcolp = enc + (size_t)b * SH + col0 + bcol;

  f32x4 acc[4][4] = {};

  for (int k0 = 0; k0 < 1024; k0 += 32) {
    const float4 a0 = *(const float4*)(arow + k0 + sc0 * 8);
    const float4 a1 = *(const float4*)(arow + k0 + sc0 * 8 + 4);
    const float4 a2 = *(const float4*)(arow + k0 + sc0 * 8 + 8);
    const float4 a3 = *(const float4*)(arow + k0 + sc0 * 8 + 12);
    float bv[2][8];
#pragma unroll
    for (int j = 0; j < 2; ++j)
#pragma unroll
      for (int i = 0; i < 8; ++i)
        bv[j][i] = bcolp[(size_t)(k0 + (kb0 + j) * 8 + i) * 1024];
    __syncthreads();
    *(short8*)&Ast[sr * 32 + ((sc0 ^ ((sr >> 1) & 3)) << 3)]       = cvt8(a0, a1);
    *(short8*)&Ast[sr * 32 + (((sc0 + 1) ^ ((sr >> 1) & 3)) << 3)] = cvt8(a2, a3);
#pragma unroll
    for (int j = 0; j < 2; ++j) {
      short8 pk;
#pragma unroll
      for (int i = 0; i < 8; ++i) pk[i] = bfr(bv[j][i]);
      *(short8*)&Bst[bcol * 32 + (((kb0 + j) ^ ((bcol >> 1) & 3)) << 3)] = pk;
    }
    __syncthreads();
    short8 af[4], bf4[4];
#pragma unroll
    for (int m = 0; m < 4; ++m) {
      const int r = wr * 64 + m * 16 + fr;
      af[m] = *(const short8*)&Ast[r * 32 + ((kg ^ ((r >> 1) & 3)) << 3)];
    }
#pragma unroll
    for (int n = 0; n < 4; ++n) {
      const int r = wc * 64 + n * 16 + fr;
      bf4[n] = *(const short8*)&Bst[r * 32 + ((kg ^ ((r >> 1) & 3)) << 3)];
    }
#pragma unroll
    for (int m = 0; m < 4; ++m)
#pragma unroll
      for (int n = 0; n < 4; ++n)
        acc[m][n] = __builtin_amdgcn_mfma_f32_16x16x32_bf16(af[m], bf4[n], acc[m][n], 0, 0, 0);
  }

  float* Cb = ctx + (size_t)b * SH;
#pragma unroll
  for (int n = 0; n < 4; ++n) {
    const int col = col0 + wc * 64 + n * 16 + fr;
#pragma unroll
    for (int m = 0; m < 4; ++m) {
      const int r0 = row0 + wr * 64 + m * 16 + kg * 4;
#pragma unroll
      for (int r = 0; r < 4; ++r)
        Cb[(size_t)(r0 + r) * 1024 + col] = acc[m][n][r];
    }
  }
}

// ---------------------------------------------------------------------------
extern "C" void kernel_launch(void* const* d_in, const int* in_sizes, int n_in,
                              void* d_out, int out_size, void* d_ws, size_t ws_size,
                              hipStream_t stream) {
  (void)in_sizes; (void)n_in; (void)out_size;
  const float* ht     = (const float*)d_in[0];
  const float* enc    = (const float*)d_in[1];
  const float* W_attn = (const float*)d_in[2];
  const float* b_attn = (const float*)d_in[3];
  // d_in[4] (W_v) is dead code in the reference

  float* ctx = (float*)d_out;          // [B,S,H] context (written last)
  float* aw  = ctx + BSH;              // [B,S,H] attention_weights (X scratch)

  // scratch parked inside the (dead-until-GEMM2) ctx region:
  short* enc_bf = (short*)ctx;                         // 32 MB, bf16 swizzled
  short* W2_bf  = (short*)(ctx + 8388608);             // 2 MB
  float* c1f    = ctx + 8388608 + 524288;              // 64 KB
  const bool big = ws_size >= ((size_t)32 << 20);
  short* encT = (short*)d_ws;                          // 32 MB (big path only)

  cvt_enc_kernel<<<8192, 256, 0, stream>>>(enc, enc_bf);
  cvt_w2_kernel<<<512, 256, 0, stream>>>(W_attn, W2_bf);
  if (big) {
    dim3 gt(16, 16, Bn);
    cvt_encT_kernel<<<gt, 256, 0, stream>>>(enc, encT);
  }
  c1_kernel<<<Bn * Hn / 4, 256, 0, stream>>>(ht, W_attn, b_attn, c1f);

  dim3 g(8, 8, Bn);
  energy_mfma2<<<g, 256, 0, stream>>>(enc_bf, W2_bf, c1f, aw);
  norm_kernel<<<Bn * 16, 256, 0, stream>>>(aw);
  if (big)
    context_fast<<<g, 256, 0, stream>>>(aw, encT, ctx);
  else
    context_mfma<<<g, 256, 0, stream>>>(aw, enc, ctx);
}